// Round 6
// baseline (704.603 us; speedup 1.0000x reference)
//
#include <hip/hip_runtime.h>
#include <math.h>

#define DIMC 192
#define C3 576
#define NHEADS 8
#define CDh 24
#define HWN 16384
#define WIDTH 128
#define NBATCH 8

typedef __attribute__((ext_vector_type(8))) short short8;
typedef __attribute__((ext_vector_type(4))) float f32x4;

__device__ __forceinline__ ushort f2bf(float f) {
    uint u = __float_as_uint(f);
    u += 0x7fff + ((u >> 16) & 1);
    return (ushort)(u >> 16);
}
__device__ __forceinline__ float bf2f(ushort h) {
    return __uint_as_float(((uint)h) << 16);
}

// ============ K0: split W_qkv -> bf16 hi/lo ============
__global__ void k0_prep(const float* __restrict__ W, ushort* __restrict__ Wh,
                        ushort* __restrict__ Wl, int n) {
    int i = blockIdx.x * 256 + threadIdx.x;
    if (i < n) {
        float w = W[i];
        ushort h = f2bf(w);
        Wh[i] = h;
        Wl[i] = f2bf(w - bf2f(h));
    }
}

// ============ K0x: transpose+split x_b -> xTh/xTl [16384 px][192 ch] bf16 ============
// grid (256 px-tiles of 64, 3 ch-tiles of 64, NZ), block 256.
__global__ __launch_bounds__(256) void k0x_tr(const float* __restrict__ x,
                                              ushort* __restrict__ xTh,
                                              ushort* __restrict__ xTl,
                                              long xT_zs, int b0) {
    __shared__ float tile[64 * 65];
    const int z = blockIdx.z;
    const float* xb = x + (size_t)(b0 + z) * DIMC * HWN;
    const int px0 = blockIdx.x * 64, ch0 = blockIdx.y * 64;
    const int tid = threadIdx.x;
#pragma unroll
    for (int it = 0; it < 16; it++) {
        int f = tid + it * 256;
        int row = f >> 6, col = f & 63;
        tile[row * 65 + col] = xb[(size_t)(ch0 + row) * HWN + px0 + col];
    }
    __syncthreads();
    uint* dh = (uint*)(xTh + (size_t)z * xT_zs);
    uint* dl = (uint*)(xTl + (size_t)z * xT_zs);
#pragma unroll
    for (int s = 0; s < 8; s++) {
        int f = tid + s * 256;
        int pxl = f >> 5, uidx = f & 31;
        float v0 = tile[(2 * uidx) * 65 + pxl];
        float v1 = tile[(2 * uidx + 1) * 65 + pxl];
        ushort h0 = f2bf(v0), h1 = f2bf(v1);
        ushort l0 = f2bf(v0 - bf2f(h0)), l1 = f2bf(v1 - bf2f(h1));
        size_t dst = (size_t)(px0 + pxl) * 96 + (ch0 >> 1) + uidx;
        dh[dst] = (uint)h0 | ((uint)h1 << 16);
        dl[dst] = (uint)l0 | ((uint)l1 << 16);
    }
}

// ============ K1m: conv1x1 via split-bf16 MFMA, no LDS, no barriers ============
// grid (256 n-tiles of 64, 3 m-tiles of 192, NZ), block 256 (4 waves; wave=48r x 64c).
__global__ __launch_bounds__(256, 3) void k1m(const ushort* __restrict__ xTh,
                                              const ushort* __restrict__ xTl,
                                              long xT_zs,
                                              const ushort* __restrict__ Wh,
                                              const ushort* __restrict__ Wl,
                                              const float* __restrict__ bias,
                                              float* __restrict__ qkv, long qkv_zs) {
    const int z = blockIdx.z;
    const ushort* xh = xTh + (size_t)z * xT_zs;
    const ushort* xl = xTl + (size_t)z * xT_zs;
    float* qz = qkv + (size_t)z * qkv_zs;
    const int n0 = blockIdx.x * 64;
    const int o0 = blockIdx.y * 192;
    const int tid = threadIdx.x;
    const int wid = tid >> 6, lane = tid & 63;
    const int lr = lane & 15, lk = lane >> 4;
    const int mb = o0 + wid * 48;
    f32x4 acc[3][4];
#pragma unroll
    for (int i = 0; i < 3; i++)
#pragma unroll
        for (int j = 0; j < 4; j++) acc[i][j] = (f32x4)0.f;

    for (int kc = 0; kc < DIMC; kc += 32) {
        short8 bh[4], bl[4];
#pragma unroll
        for (int j = 0; j < 4; j++) {
            size_t boff = (size_t)(n0 + j * 16 + lr) * DIMC + kc + lk * 8;
            bh[j] = *(const short8*)&xh[boff];
            bl[j] = *(const short8*)&xl[boff];
        }
#pragma unroll
        for (int i = 0; i < 3; i++) {
            size_t aoff = (size_t)(mb + i * 16 + lr) * DIMC + kc + lk * 8;
            const short8 ah = *(const short8*)&Wh[aoff];
            const short8 al = *(const short8*)&Wl[aoff];
#pragma unroll
            for (int j = 0; j < 4; j++) {
                acc[i][j] = __builtin_amdgcn_mfma_f32_16x16x32_bf16(ah, bh[j], acc[i][j], 0, 0, 0);
                acc[i][j] = __builtin_amdgcn_mfma_f32_16x16x32_bf16(ah, bl[j], acc[i][j], 0, 0, 0);
                acc[i][j] = __builtin_amdgcn_mfma_f32_16x16x32_bf16(al, bh[j], acc[i][j], 0, 0, 0);
            }
        }
    }
#pragma unroll
    for (int i = 0; i < 3; i++) {
        int rbase = mb + i * 16 + lk * 4;
#pragma unroll
        for (int r = 0; r < 4; r++) {
            int row = rbase + r;
            float bsv = bias[row];
#pragma unroll
            for (int j = 0; j < 4; j++) {
                qz[(size_t)row * HWN + n0 + j * 16 + lr] = acc[i][j][r] + bsv;
            }
        }
    }
}

// ============ K2: depthwise 3x3 + Gram/sumsq partials; v -> fp32 OR transposed split-bf16 ============
// grid (32 stripes of 4 rows, 8 heads, NZ), block 1024 (16 waves).
__global__ __launch_bounds__(1024, 4) void k2_dw(const float* __restrict__ qkv0, long qkv_zs,
                                                 const float* __restrict__ wdw,
                                                 const float* __restrict__ bdw,
                                                 float* __restrict__ vout,
                                                 ushort* __restrict__ vTh,
                                                 ushort* __restrict__ vTl,
                                                 float* __restrict__ part,
                                                 int b0, int vt) {
    __shared__ float stage[6336];       // [8][6][132]; v-transpose reuse: [8][516]
    __shared__ float qks[48 * 520];     // [qk ch][512 px + pad], fp32
    const int b = b0 + blockIdx.z;
    const float* qkv = qkv0 + (size_t)blockIdx.z * qkv_zs;
    const int stripe = blockIdx.x, h = blockIdx.y;
    const int tid = threadIdx.x;
    const int r0 = stripe * 4;

    const int col4 = (tid & 31) * 4;
    const int orow = (tid >> 5) & 3;
    const int cc = tid >> 7;  // 0..7

    for (int chunk = 0; chunk < 9; chunk++) {
        const int g = chunk / 3, cb = (chunk % 3) * 8;
        __syncthreads();
#pragma unroll
        for (int f = tid; f < 1536; f += 1024) {
            int fc = f / 192, rem = f - fc * 192;
            int rl = rem >> 5, c4 = rem & 31;
            int gr = r0 - 1 + rl;
            int ch = g * DIMC + h * CDh + cb + fc;
            float4 v = make_float4(0.f, 0.f, 0.f, 0.f);
            if (gr >= 0 && gr < 128)
                v = *(const float4*)&qkv[(size_t)ch * HWN + gr * WIDTH + c4 * 4];
            *(float4*)&stage[(fc * 6 + rl) * 132 + c4 * 4] = v;
        }
        __syncthreads();
        float a0, a1, a2, a3;
        {
            const int ch = g * DIMC + h * CDh + cb + cc;
            float wr[9];
#pragma unroll
            for (int t = 0; t < 9; t++) wr[t] = wdw[ch * 9 + t];
            float bsv = bdw[ch];
            a0 = bsv; a1 = bsv; a2 = bsv; a3 = bsv;
#pragma unroll
            for (int dr = 0; dr < 3; dr++) {
                const float* row = &stage[(cc * 6 + orow + dr) * 132];
                float left = (col4 > 0) ? row[col4 - 1] : 0.f;
                float4 c = *(const float4*)&row[col4];
                float right = (col4 < 124) ? row[col4 + 4] : 0.f;
                float wA = wr[dr * 3 + 0], wB = wr[dr * 3 + 1], wC = wr[dr * 3 + 2];
                a0 = fmaf(left, wA, fmaf(c.x, wB, fmaf(c.y, wC, a0)));
                a1 = fmaf(c.x, wA, fmaf(c.y, wB, fmaf(c.z, wC, a1)));
                a2 = fmaf(c.y, wA, fmaf(c.z, wB, fmaf(c.w, wC, a2)));
                a3 = fmaf(c.z, wA, fmaf(c.w, wB, fmaf(right, wC, a3)));
            }
        }
        if (g < 2) {
            float4 o4 = {a0, a1, a2, a3};
            *(float4*)&qks[(g * CDh + cb + cc) * 520 + orow * 128 + col4] = o4;
        } else if (!vt) {
            float4 o4 = {a0, a1, a2, a3};
            *(float4*)&vout[((size_t)b * DIMC + h * CDh + cb + cc) * HWN +
                            (size_t)(r0 + orow) * WIDTH + col4] = o4;
        } else {
            // transposed split-bf16 v via LDS (stage reused as [8][516])
            __syncthreads();  // all conv reads of stage complete
            stage[cc * 516 + orow * 128 + col4 + 0] = a0;
            stage[cc * 516 + orow * 128 + col4 + 1] = a1;
            stage[cc * 516 + orow * 128 + col4 + 2] = a2;
            stage[cc * 516 + orow * 128 + col4 + 3] = a3;
            __syncthreads();
            const int pxl = tid >> 1, is_lo = tid & 1;
            float vals[8];
#pragma unroll
            for (int c = 0; c < 8; c++) vals[c] = stage[c * 516 + pxl];
            ushort s[8];
#pragma unroll
            for (int c = 0; c < 8; c++) {
                ushort hb = f2bf(vals[c]);
                s[c] = is_lo ? f2bf(vals[c] - bf2f(hb)) : hb;
            }
            uint4 o;
            o.x = (uint)s[0] | ((uint)s[1] << 16);
            o.y = (uint)s[2] | ((uint)s[3] << 16);
            o.z = (uint)s[4] | ((uint)s[5] << 16);
            o.w = (uint)s[6] | ((uint)s[7] << 16);
            const size_t px_g = (size_t)b * HWN + r0 * WIDTH + pxl;
            uint4* dst = (uint4*)(is_lo ? vTl : vTh);
            dst[px_g * 24 + h * 3 + (cb >> 3)] = o;
        }
    }
    __syncthreads();  // qks complete

    const int tc = tid & 3, td = (tid >> 2) & 3, tp = tid >> 4;
    float ga[6][6];
#pragma unroll
    for (int i = 0; i < 6; i++)
#pragma unroll
        for (int j = 0; j < 6; j++) ga[i][j] = 0.f;
#pragma unroll
    for (int s = 0; s < 2; s++) {
        int px = tp * 8 + s * 4;
        f32x4 qv[6], kv[6];
#pragma unroll
        for (int i = 0; i < 6; i++) qv[i] = *(const f32x4*)&qks[(tc * 6 + i) * 520 + px];
#pragma unroll
        for (int j = 0; j < 6; j++) kv[j] = *(const f32x4*)&qks[(24 + td * 6 + j) * 520 + px];
#pragma unroll
        for (int i = 0; i < 6; i++)
#pragma unroll
            for (int j = 0; j < 6; j++) {
                ga[i][j] = fmaf(qv[i][0], kv[j][0], ga[i][j]);
                ga[i][j] = fmaf(qv[i][1], kv[j][1], ga[i][j]);
                ga[i][j] = fmaf(qv[i][2], kv[j][2], ga[i][j]);
                ga[i][j] = fmaf(qv[i][3], kv[j][3], ga[i][j]);
            }
    }
#pragma unroll
    for (int i = 0; i < 6; i++)
#pragma unroll
        for (int j = 0; j < 6; j++) {
            float v = ga[i][j];
            v += __shfl_xor(v, 16, 64);
            v += __shfl_xor(v, 32, 64);
            ga[i][j] = v;
        }
    float nv = 0.f;
    int nch = 0, npg = 0;
    if (tid < 768) {
        npg = tid / 48;
        nch = tid - npg * 48;
#pragma unroll
        for (int s = 0; s < 8; s++) {
            f32x4 v = *(const f32x4*)&qks[nch * 520 + npg * 32 + s * 4];
            nv = fmaf(v[0], v[0], nv);
            nv = fmaf(v[1], v[1], nv);
            nv = fmaf(v[2], v[2], nv);
            nv = fmaf(v[3], v[3], nv);
        }
    }
    __syncthreads();
    float* gscr = qks;  // [16][624]
    const int wave = tid >> 6;
    if ((tid & 63) < 16) {
#pragma unroll
        for (int i = 0; i < 6; i++)
#pragma unroll
            for (int j = 0; j < 6; j++)
                gscr[wave * 624 + (tc * 6 + i) * 24 + (td * 6 + j)] = ga[i][j];
    }
    if (tid < 768) gscr[npg * 624 + 576 + nch] = nv;
    __syncthreads();
    if (tid < 624) {
        float s = 0.f;
#pragma unroll
        for (int w2 = 0; w2 < 16; w2++) s += gscr[w2 * 624 + tid];
        part[((size_t)(b * NHEADS + h) * 624 + tid) * 32 + stripe] = s;
    }
}

// ============ K34: reduce partials + attn + 4 top-k softmaxes -> A_eff (fused) ============
// grid 64 (bh), block 256.
__global__ void k34_attn(const float* __restrict__ part, const float* __restrict__ temp,
                         const float* __restrict__ a1, const float* __restrict__ a2,
                         const float* __restrict__ a3, const float* __restrict__ a4,
                         float* __restrict__ Aeff) {
    __shared__ float gbuf[624];
    int bh = blockIdx.x;
    int h = bh & 7;
    int tid = threadIdx.x;
    int lane = tid & 63, wave = tid >> 6;
    int half = lane >> 5, sl = lane & 31;
    for (int tp = wave; tp < 312; tp += 4) {
        int ti = tp * 2 + half;
        float v = part[((size_t)bh * 624 + ti) * 32 + sl];
        v += __shfl_xor(v, 1, 64);
        v += __shfl_xor(v, 2, 64);
        v += __shfl_xor(v, 4, 64);
        v += __shfl_xor(v, 8, 64);
        v += __shfl_xor(v, 16, 64);
        if (sl == 0) gbuf[ti] = v;
    }
    __syncthreads();
    int r = tid;
    if (r >= CDh) return;
    float t = temp[h];
    float aw[4] = {a1[0], a2[0], a3[0], a4[0]};
    const int kks[4] = {12, 16, 18, 19};
    float qn = fmaxf(sqrtf(gbuf[576 + r]), 1e-12f);
    float av[24];
    for (int d = 0; d < 24; d++) {
        float kn = fmaxf(sqrtf(gbuf[600 + d]), 1e-12f);
        av[d] = gbuf[r * 24 + d] / (qn * kn) * t;
    }
    int rank[24];
    float m = -1e30f;
    for (int d = 0; d < 24; d++) {
        int rk = 0;
        for (int e = 0; e < 24; e++)
            rk += (av[e] > av[d]) || (av[e] == av[d] && e < d);
        rank[d] = rk;
        m = fmaxf(m, av[d]);
    }
    float ex[24], outv[24];
    for (int d = 0; d < 24; d++) { ex[d] = expf(av[d] - m); outv[d] = 0.f; }
    for (int i = 0; i < 4; i++) {
        float Z = 0.f;
        for (int d = 0; d < 24; d++) if (rank[d] < kks[i]) Z += ex[d];
        float inv = aw[i] / Z;
        for (int d = 0; d < 24; d++) if (rank[d] < kks[i]) outv[d] += ex[d] * inv;
    }
    for (int d = 0; d < 24; d++) Aeff[(bh * 24 + r) * 24 + d] = outv[d];
}

// ============ K4b: M_b = W_proj @ blockdiag(A_eff) -> bf16 hi/lo ============
__global__ void k4b_mmat(const float* __restrict__ Wp, const float* __restrict__ Aeff,
                         ushort* __restrict__ Mh, ushort* __restrict__ Ml) {
    int b = blockIdx.x;
    int e0 = blockIdx.y * 6144;
    for (int e = e0 + threadIdx.x; e < e0 + 6144; e += 256) {
        int o = e / DIMC, j = e % DIMC;
        int h = j / CDh, d = j % CDh;
        const float* wrow = Wp + o * DIMC + h * CDh;
        const float* acol = Aeff + (size_t)((b * NHEADS + h) * CDh) * CDh + d;
        float s = 0.f;
        for (int c = 0; c < CDh; c++) s = fmaf(wrow[c], acol[c * CDh], s);
        size_t idx = ((size_t)b * DIMC + o) * DIMC + j;
        ushort hb = f2bf(s);
        Mh[idx] = hb;
        Ml[idx] = f2bf(s - bf2f(hb));
    }
}

// ============ K5v: y = M_b @ v + b_proj, pure MFMA from vT (k1m clone) ============
// grid (256 n-tiles of 64, 8 b), block 256 (4 waves; wave = 48 rows x 64 cols).
__global__ __launch_bounds__(256, 3) void k5v(const ushort* __restrict__ vTh,
                                              const ushort* __restrict__ vTl,
                                              const ushort* __restrict__ Mh,
                                              const ushort* __restrict__ Ml,
                                              const float* __restrict__ bias,
                                              float* __restrict__ y) {
    const int z = blockIdx.y;
    const ushort* vh = vTh + (size_t)z * DIMC * HWN;
    const ushort* vl = vTl + (size_t)z * DIMC * HWN;
    const ushort* Mhz = Mh + (size_t)z * DIMC * DIMC;
    const ushort* Mlz = Ml + (size_t)z * DIMC * DIMC;
    float* yb = y + (size_t)z * DIMC * HWN;
    const int n0 = blockIdx.x * 64;
    const int tid = threadIdx.x;
    const int wid = tid >> 6, lane = tid & 63;
    const int lr = lane & 15, lk = lane >> 4;
    const int mb = wid * 48;
    f32x4 acc[3][4];
#pragma unroll
    for (int i = 0; i < 3; i++)
#pragma unroll
        for (int j = 0; j < 4; j++) acc[i][j] = (f32x4)0.f;

    for (int kc = 0; kc < DIMC; kc += 32) {
        short8 bh[4], bl[4];
#pragma unroll
        for (int j = 0; j < 4; j++) {
            size_t boff = (size_t)(n0 + j * 16 + lr) * DIMC + kc + lk * 8;
            bh[j] = *(const short8*)&vh[boff];
            bl[j] = *(const short8*)&vl[boff];
        }
#pragma unroll
        for (int i = 0; i < 3; i++) {
            size_t aoff = (size_t)(mb + i * 16 + lr) * DIMC + kc + lk * 8;
            const short8 ah = *(const short8*)&Mhz[aoff];
            const short8 al = *(const short8*)&Mlz[aoff];
#pragma unroll
            for (int j = 0; j < 4; j++) {
                acc[i][j] = __builtin_amdgcn_mfma_f32_16x16x32_bf16(ah, bh[j], acc[i][j], 0, 0, 0);
                acc[i][j] = __builtin_amdgcn_mfma_f32_16x16x32_bf16(ah, bl[j], acc[i][j], 0, 0, 0);
                acc[i][j] = __builtin_amdgcn_mfma_f32_16x16x32_bf16(al, bh[j], acc[i][j], 0, 0, 0);
            }
        }
    }
#pragma unroll
    for (int i = 0; i < 3; i++) {
        int rbase = mb + i * 16 + lk * 4;
#pragma unroll
        for (int r = 0; r < 4; r++) {
            int row = rbase + r;
            float bsv = bias[row];
#pragma unroll
            for (int j = 0; j < 4; j++) {
                yb[(size_t)row * HWN + n0 + j * 16 + lr] = acc[i][j][r] + bsv;
            }
        }
    }
}

// ============ K5m fallback: in-place on d_out with LDS convert (R5-proven) ============
__global__ __launch_bounds__(256) void k5m(float* vy,
                                           const ushort* __restrict__ Mh,
                                           const ushort* __restrict__ Ml,
                                           const float* __restrict__ bias) {
    __shared__ float Bs[32 * 132];
    const int z = blockIdx.y;
    float* vb = vy + (size_t)z * DIMC * HWN;
    const ushort* Mhz = Mh + (size_t)z * DIMC * DIMC;
    const ushort* Mlz = Ml + (size_t)z * DIMC * DIMC;
    const int n0 = blockIdx.x * 128;
    const int tid = threadIdx.x;
    const int wid = tid >> 6, lane = tid & 63;
    const int lr = lane & 15, lk = lane >> 4;
    const int mb = wid * 48;
    f32x4 acc[3][8];
#pragma unroll
    for (int i = 0; i < 3; i++)
#pragma unroll
        for (int j = 0; j < 8; j++) acc[i][j] = (f32x4)0.f;

    for (int kc = 0; kc < DIMC; kc += 32) {
        __syncthreads();
#pragma unroll
        for (int it = 0; it < 4; it++) {
            int f4 = tid + it * 256;
            int r = f4 >> 5, c4 = (f4 & 31) * 4;
            *(f32x4*)&Bs[r * 132 + c4] =
                *(const f32x4*)&vb[(size_t)(kc + r) * HWN + n0 + c4];
        }
        __syncthreads();
        short8 bh[8], bl[8];
#pragma unroll
        for (int j = 0; j < 8; j++) {
            int n = j * 16 + lr;
            union { short8 s; uint u[4]; } H, L;
#pragma unroll
            for (int p = 0; p < 4; p++) {
                float v0 = Bs[(lk * 8 + 2 * p) * 132 + n];
                float v1 = Bs[(lk * 8 + 2 * p + 1) * 132 + n];
                ushort h0 = f2bf(v0), h1 = f2bf(v1);
                ushort l0 = f2bf(v0 - bf2f(h0)), l1 = f2bf(v1 - bf2f(h1));
                H.u[p] = (uint)h0 | ((uint)h1 << 16);
                L.u[p] = (uint)l0 | ((uint)l1 << 16);
            }
            bh[j] = H.s; bl[j] = L.s;
        }
#pragma unroll
        for (int i = 0; i < 3; i++) {
            size_t aoff = (size_t)(mb + i * 16 + lr) * DIMC + kc + lk * 8;
            const short8 ah = *(const short8*)&Mhz[aoff];
            const short8 al = *(const short8*)&Mlz[aoff];
#pragma unroll
            for (int j = 0; j < 8; j++) {
                acc[i][j] = __builtin_amdgcn_mfma_f32_16x16x32_bf16(ah, bh[j], acc[i][j], 0, 0, 0);
                acc[i][j] = __builtin_amdgcn_mfma_f32_16x16x32_bf16(ah, bl[j], acc[i][j], 0, 0, 0);
                acc[i][j] = __builtin_amdgcn_mfma_f32_16x16x32_bf16(al, bh[j], acc[i][j], 0, 0, 0);
            }
        }
    }
    __syncthreads();
#pragma unroll
    for (int i = 0; i < 3; i++) {
        int rbase = mb + i * 16 + lk * 4;
#pragma unroll
        for (int r = 0; r < 4; r++) {
            int row = rbase + r;
            float bsv = bias[row];
#pragma unroll
            for (int j = 0; j < 8; j++) {
                vb[(size_t)row * HWN + n0 + j * 16 + lr] = acc[i][j][r] + bsv;
            }
        }
    }
}

extern "C" void kernel_launch(void* const* d_in, const int* in_sizes, int n_in,
                              void* d_out, int out_size, void* d_ws, size_t ws_size,
                              hipStream_t stream) {
    const float* x     = (const float*)d_in[0];
    const float* wqkv  = (const float*)d_in[1];
    const float* bqkv  = (const float*)d_in[2];
    const float* wdw   = (const float*)d_in[3];
    const float* bdw   = (const float*)d_in[4];
    const float* wproj = (const float*)d_in[5];
    const float* bproj = (const float*)d_in[6];
    const float* temp  = (const float*)d_in[7];
    const float* a1    = (const float*)d_in[8];
    const float* a2    = (const float*)d_in[9];
    const float* a3    = (const float*)d_in[10];
    const float* a4    = (const float*)d_in[11];
    float* out = (float*)d_out;

    float* ws = (float*)d_ws;
    // float-unit offsets
    const size_t fl_part = (size_t)64 * 624 * 32;        // 1,277,952
    const size_t fl_A    = (size_t)64 * 576;             // 36,864
    const size_t fl_M    = (size_t)NBATCH * DIMC * DIMC / 2;  // 147,456
    const size_t fl_W    = (size_t)C3 * DIMC / 2;        // 55,296
    const size_t fl_xT1  = (size_t)DIMC * HWN / 2;       // 1,572,864 (one bf16 buf, one batch)
    const size_t fl_qkv1 = (size_t)C3 * HWN;             // 9,437,184
    const size_t fl_vT1  = (size_t)NBATCH * DIMC * HWN / 2;  // 12,582,912 (one buf, all batches)

    const size_t base_fl = fl_part + fl_A + 2 * fl_M + 2 * fl_W;  // 1,720,320

    // tier selection
    auto need = [&](int vt, int nz) -> size_t {
        return (base_fl + (size_t)nz * (2 * fl_xT1 + fl_qkv1) + (vt ? 2 * fl_vT1 : 0)) *
               sizeof(float);
    };
    int vt, nz;
    if (ws_size >= need(1, 2))      { vt = 1; nz = 2; }
    else if (ws_size >= need(1, 1)) { vt = 1; nz = 1; }
    else if (ws_size >= need(0, 2)) { vt = 0; nz = 2; }
    else                            { vt = 0; nz = 1; }

    size_t o = 0;
    float* part = ws + o; o += fl_part;
    float* Aeff = ws + o; o += fl_A;
    ushort* Mh  = (ushort*)(ws + o); o += fl_M;
    ushort* Ml  = (ushort*)(ws + o); o += fl_M;
    ushort* Wh  = (ushort*)(ws + o); o += fl_W;
    ushort* Wl  = (ushort*)(ws + o); o += fl_W;
    ushort* xTh = (ushort*)(ws + o); o += (size_t)nz * fl_xT1;
    ushort* xTl = (ushort*)(ws + o); o += (size_t)nz * fl_xT1;
    float* qkv  = ws + o; o += (size_t)nz * fl_qkv1;
    ushort* vTh = (ushort*)(ws + o); o += vt ? fl_vT1 : 0;
    ushort* vTl = (ushort*)(ws + o);

    const long xT_zs  = (long)DIMC * HWN;   // ushorts per batch
    const long qkv_zs = (long)fl_qkv1;      // floats per batch

    k0_prep<<<(C3 * DIMC + 255) / 256, 256, 0, stream>>>(wqkv, Wh, Wl, C3 * DIMC);

    for (int b0 = 0; b0 < NBATCH; b0 += nz) {
        k0x_tr<<<dim3(256, 3, nz), 256, 0, stream>>>(x, xTh, xTl, xT_zs, b0);
        k1m<<<dim3(256, 3, nz), 256, 0, stream>>>(xTh, xTl, xT_zs, Wh, Wl, bqkv,
                                                  qkv, qkv_zs);
        k2_dw<<<dim3(32, 8, nz), 1024, 0, stream>>>(qkv, qkv_zs, wdw, bdw, out,
                                                    vTh, vTl, part, b0, vt);
    }
    k34_attn<<<64, 256, 0, stream>>>(part, temp, a1, a2, a3, a4, Aeff);
    k4b_mmat<<<dim3(8, 6), 256, 0, stream>>>(wproj, Aeff, Mh, Ml);
    if (vt) {
        k5v<<<dim3(256, 8), 256, 0, stream>>>(vTh, vTl, Mh, Ml, bproj, out);
    } else {
        k5m<<<dim3(128, 8), 256, 0, stream>>>(out, Mh, Ml, bproj);
    }
}

// Round 7
// 603.146 us; speedup vs baseline: 1.1682x; 1.1682x over previous
//
#include <hip/hip_runtime.h>
#include <math.h>

#define DIMC 192
#define C3 576
#define NHEADS 8
#define CDh 24
#define HWN 16384
#define WIDTH 128
#define NBATCH 8

typedef __attribute__((ext_vector_type(8))) short short8;
typedef __attribute__((ext_vector_type(4))) float f32x4;

__device__ __forceinline__ ushort f2bf(float f) {
    uint u = __float_as_uint(f);
    u += 0x7fff + ((u >> 16) & 1);
    return (ushort)(u >> 16);
}
__device__ __forceinline__ float bf2f(ushort h) {
    return __uint_as_float(((uint)h) << 16);
}

// ============ K0: split W_qkv -> bf16 hi/lo ============
__global__ void k0_prep(const float* __restrict__ W, ushort* __restrict__ Wh,
                        ushort* __restrict__ Wl, int n) {
    int i = blockIdx.x * 256 + threadIdx.x;
    if (i < n) {
        float w = W[i];
        ushort h = f2bf(w);
        Wh[i] = h;
        Wl[i] = f2bf(w - bf2f(h));
    }
}

// ============ K0x: transpose+split x_b -> xTh/xTl [16384 px][192 ch] bf16 ============
__global__ __launch_bounds__(256) void k0x_tr(const float* __restrict__ x,
                                              ushort* __restrict__ xTh,
                                              ushort* __restrict__ xTl,
                                              long xT_zs, int b0) {
    __shared__ float tile[64 * 65];
    const int z = blockIdx.z;
    const float* xb = x + (size_t)(b0 + z) * DIMC * HWN;
    const int px0 = blockIdx.x * 64, ch0 = blockIdx.y * 64;
    const int tid = threadIdx.x;
#pragma unroll
    for (int it = 0; it < 16; it++) {
        int f = tid + it * 256;
        int row = f >> 6, col = f & 63;
        tile[row * 65 + col] = xb[(size_t)(ch0 + row) * HWN + px0 + col];
    }
    __syncthreads();
    uint* dh = (uint*)(xTh + (size_t)z * xT_zs);
    uint* dl = (uint*)(xTl + (size_t)z * xT_zs);
#pragma unroll
    for (int s = 0; s < 8; s++) {
        int f = tid + s * 256;
        int pxl = f >> 5, uidx = f & 31;
        float v0 = tile[(2 * uidx) * 65 + pxl];
        float v1 = tile[(2 * uidx + 1) * 65 + pxl];
        ushort h0 = f2bf(v0), h1 = f2bf(v1);
        ushort l0 = f2bf(v0 - bf2f(h0)), l1 = f2bf(v1 - bf2f(h1));
        size_t dst = (size_t)(px0 + pxl) * 96 + (ch0 >> 1) + uidx;
        dh[dst] = (uint)h0 | ((uint)h1 << 16);
        dl[dst] = (uint)l0 | ((uint)l1 << 16);
    }
}

// ============ KG<NI>: C = A @ B^T via split-bf16 MFMA, B-tile resident in LDS ============
// grid (256 n-tiles of 64 px, 1, NZ), block 256 (4 waves; wave = NI*16 rows x 64 px).
// B layout [px][192] bf16 hi/lo (pre-transposed). A layout [row][192] bf16 hi/lo.
// One barrier total; K-loop reads B from LDS (padded stride 200), A from global (L2-hot).
template <int NI>
__global__ __launch_bounds__(256, (NI == 9) ? 2 : 3) void kg(
    const ushort* __restrict__ Bh, const ushort* __restrict__ Bl, long B_zs,
    const ushort* __restrict__ Ah, const ushort* __restrict__ Al, long A_zs,
    const float* __restrict__ bias, float* __restrict__ out, long out_zs) {
    __shared__ ushort BsH[64 * 200];
    __shared__ ushort BsL[64 * 200];
    const int z = blockIdx.z;
    const int n0 = blockIdx.x * 64;
    const int tid = threadIdx.x;
    const ushort* sh = Bh + (size_t)z * B_zs + (size_t)n0 * DIMC;
    const ushort* sl = Bl + (size_t)z * B_zs + (size_t)n0 * DIMC;
#pragma unroll
    for (int it = 0; it < 6; it++) {
        int f = tid + it * 256;
        int px = f / 24, oct = f - px * 24;
        *(short8*)&BsH[px * 200 + oct * 8] = *(const short8*)&sh[(size_t)px * DIMC + oct * 8];
        *(short8*)&BsL[px * 200 + oct * 8] = *(const short8*)&sl[(size_t)px * DIMC + oct * 8];
    }
    __syncthreads();
    const int wid = tid >> 6, lane = tid & 63;
    const int lr = lane & 15, lk = lane >> 4;
    const int mb = wid * (NI * 16);
    const ushort* Azh = Ah + (size_t)z * A_zs;
    const ushort* Azl = Al + (size_t)z * A_zs;
    float* oz = out + (size_t)z * out_zs;
    f32x4 acc[NI][4];
#pragma unroll
    for (int i = 0; i < NI; i++)
#pragma unroll
        for (int j = 0; j < 4; j++) acc[i][j] = (f32x4)0.f;

    for (int kc6 = 0; kc6 < 6; kc6++) {
        short8 bh[4], bl[4];
#pragma unroll
        for (int j = 0; j < 4; j++) {
            int ad = (j * 16 + lr) * 200 + kc6 * 32 + lk * 8;
            bh[j] = *(const short8*)&BsH[ad];
            bl[j] = *(const short8*)&BsL[ad];
        }
#pragma unroll
        for (int i = 0; i < NI; i++) {
            size_t ao = (size_t)(mb + i * 16 + lr) * DIMC + kc6 * 32 + lk * 8;
            const short8 ah = *(const short8*)&Azh[ao];
            const short8 al = *(const short8*)&Azl[ao];
#pragma unroll
            for (int j = 0; j < 4; j++) {
                acc[i][j] = __builtin_amdgcn_mfma_f32_16x16x32_bf16(ah, bh[j], acc[i][j], 0, 0, 0);
                acc[i][j] = __builtin_amdgcn_mfma_f32_16x16x32_bf16(ah, bl[j], acc[i][j], 0, 0, 0);
                acc[i][j] = __builtin_amdgcn_mfma_f32_16x16x32_bf16(al, bh[j], acc[i][j], 0, 0, 0);
            }
        }
    }
#pragma unroll
    for (int i = 0; i < NI; i++) {
        int rb = mb + i * 16 + lk * 4;
#pragma unroll
        for (int r = 0; r < 4; r++) {
            int row = rb + r;
            float bsv = bias[row];
#pragma unroll
            for (int j = 0; j < 4; j++)
                oz[(size_t)row * HWN + n0 + j * 16 + lr] = acc[i][j][r] + bsv;
        }
    }
}

// ============ K2: depthwise 3x3 + Gram/sumsq partials; v -> fp32 OR transposed split-bf16 ============
__global__ __launch_bounds__(1024, 4) void k2_dw(const float* __restrict__ qkv0, long qkv_zs,
                                                 const float* __restrict__ wdw,
                                                 const float* __restrict__ bdw,
                                                 float* __restrict__ vout,
                                                 ushort* __restrict__ vTh,
                                                 ushort* __restrict__ vTl,
                                                 float* __restrict__ part,
                                                 int b0, int vt) {
    __shared__ float stage[6336];       // [8][6][132]; v-transpose reuse: [8][516]
    __shared__ float qks[48 * 520];     // [qk ch][512 px + pad], fp32
    const int b = b0 + blockIdx.z;
    const float* qkv = qkv0 + (size_t)blockIdx.z * qkv_zs;
    const int stripe = blockIdx.x, h = blockIdx.y;
    const int tid = threadIdx.x;
    const int r0 = stripe * 4;

    const int col4 = (tid & 31) * 4;
    const int orow = (tid >> 5) & 3;
    const int cc = tid >> 7;  // 0..7

    for (int chunk = 0; chunk < 9; chunk++) {
        const int g = chunk / 3, cb = (chunk % 3) * 8;
        __syncthreads();
#pragma unroll
        for (int f = tid; f < 1536; f += 1024) {
            int fc = f / 192, rem = f - fc * 192;
            int rl = rem >> 5, c4 = rem & 31;
            int gr = r0 - 1 + rl;
            int ch = g * DIMC + h * CDh + cb + fc;
            float4 v = make_float4(0.f, 0.f, 0.f, 0.f);
            if (gr >= 0 && gr < 128)
                v = *(const float4*)&qkv[(size_t)ch * HWN + gr * WIDTH + c4 * 4];
            *(float4*)&stage[(fc * 6 + rl) * 132 + c4 * 4] = v;
        }
        __syncthreads();
        float a0, a1, a2, a3;
        {
            const int ch = g * DIMC + h * CDh + cb + cc;
            float wr[9];
#pragma unroll
            for (int t = 0; t < 9; t++) wr[t] = wdw[ch * 9 + t];
            float bsv = bdw[ch];
            a0 = bsv; a1 = bsv; a2 = bsv; a3 = bsv;
#pragma unroll
            for (int dr = 0; dr < 3; dr++) {
                const float* row = &stage[(cc * 6 + orow + dr) * 132];
                float left = (col4 > 0) ? row[col4 - 1] : 0.f;
                float4 c = *(const float4*)&row[col4];
                float right = (col4 < 124) ? row[col4 + 4] : 0.f;
                float wA = wr[dr * 3 + 0], wB = wr[dr * 3 + 1], wC = wr[dr * 3 + 2];
                a0 = fmaf(left, wA, fmaf(c.x, wB, fmaf(c.y, wC, a0)));
                a1 = fmaf(c.x, wA, fmaf(c.y, wB, fmaf(c.z, wC, a1)));
                a2 = fmaf(c.y, wA, fmaf(c.z, wB, fmaf(c.w, wC, a2)));
                a3 = fmaf(c.z, wA, fmaf(c.w, wB, fmaf(right, wC, a3)));
            }
        }
        if (g < 2) {
            float4 o4 = {a0, a1, a2, a3};
            *(float4*)&qks[(g * CDh + cb + cc) * 520 + orow * 128 + col4] = o4;
        } else if (!vt) {
            float4 o4 = {a0, a1, a2, a3};
            *(float4*)&vout[((size_t)b * DIMC + h * CDh + cb + cc) * HWN +
                            (size_t)(r0 + orow) * WIDTH + col4] = o4;
        } else {
            __syncthreads();  // all conv reads of stage complete
            stage[cc * 516 + orow * 128 + col4 + 0] = a0;
            stage[cc * 516 + orow * 128 + col4 + 1] = a1;
            stage[cc * 516 + orow * 128 + col4 + 2] = a2;
            stage[cc * 516 + orow * 128 + col4 + 3] = a3;
            __syncthreads();
            const int pxl = tid >> 1, is_lo = tid & 1;
            float vals[8];
#pragma unroll
            for (int c = 0; c < 8; c++) vals[c] = stage[c * 516 + pxl];
            ushort s[8];
#pragma unroll
            for (int c = 0; c < 8; c++) {
                ushort hb = f2bf(vals[c]);
                s[c] = is_lo ? f2bf(vals[c] - bf2f(hb)) : hb;
            }
            uint4 o;
            o.x = (uint)s[0] | ((uint)s[1] << 16);
            o.y = (uint)s[2] | ((uint)s[3] << 16);
            o.z = (uint)s[4] | ((uint)s[5] << 16);
            o.w = (uint)s[6] | ((uint)s[7] << 16);
            const size_t px_g = (size_t)b * HWN + r0 * WIDTH + pxl;
            uint4* dst = (uint4*)(is_lo ? vTl : vTh);
            dst[px_g * 24 + h * 3 + (cb >> 3)] = o;
        }
    }
    __syncthreads();  // qks complete

    const int tc = tid & 3, td = (tid >> 2) & 3, tp = tid >> 4;
    float ga[6][6];
#pragma unroll
    for (int i = 0; i < 6; i++)
#pragma unroll
        for (int j = 0; j < 6; j++) ga[i][j] = 0.f;
#pragma unroll
    for (int s = 0; s < 2; s++) {
        int px = tp * 8 + s * 4;
        f32x4 qv[6], kv[6];
#pragma unroll
        for (int i = 0; i < 6; i++) qv[i] = *(const f32x4*)&qks[(tc * 6 + i) * 520 + px];
#pragma unroll
        for (int j = 0; j < 6; j++) kv[j] = *(const f32x4*)&qks[(24 + td * 6 + j) * 520 + px];
#pragma unroll
        for (int i = 0; i < 6; i++)
#pragma unroll
            for (int j = 0; j < 6; j++) {
                ga[i][j] = fmaf(qv[i][0], kv[j][0], ga[i][j]);
                ga[i][j] = fmaf(qv[i][1], kv[j][1], ga[i][j]);
                ga[i][j] = fmaf(qv[i][2], kv[j][2], ga[i][j]);
                ga[i][j] = fmaf(qv[i][3], kv[j][3], ga[i][j]);
            }
    }
#pragma unroll
    for (int i = 0; i < 6; i++)
#pragma unroll
        for (int j = 0; j < 6; j++) {
            float v = ga[i][j];
            v += __shfl_xor(v, 16, 64);
            v += __shfl_xor(v, 32, 64);
            ga[i][j] = v;
        }
    float nv = 0.f;
    int nch = 0, npg = 0;
    if (tid < 768) {
        npg = tid / 48;
        nch = tid - npg * 48;
#pragma unroll
        for (int s = 0; s < 8; s++) {
            f32x4 v = *(const f32x4*)&qks[nch * 520 + npg * 32 + s * 4];
            nv = fmaf(v[0], v[0], nv);
            nv = fmaf(v[1], v[1], nv);
            nv = fmaf(v[2], v[2], nv);
            nv = fmaf(v[3], v[3], nv);
        }
    }
    __syncthreads();
    float* gscr = qks;  // [16][624]
    const int wave = tid >> 6;
    if ((tid & 63) < 16) {
#pragma unroll
        for (int i = 0; i < 6; i++)
#pragma unroll
            for (int j = 0; j < 6; j++)
                gscr[wave * 624 + (tc * 6 + i) * 24 + (td * 6 + j)] = ga[i][j];
    }
    if (tid < 768) gscr[npg * 624 + 576 + nch] = nv;
    __syncthreads();
    if (tid < 624) {
        float s = 0.f;
#pragma unroll
        for (int w2 = 0; w2 < 16; w2++) s += gscr[w2 * 624 + tid];
        part[((size_t)(b * NHEADS + h) * 624 + tid) * 32 + stripe] = s;
    }
}

// ============ K34: reduce partials + attn + 4 top-k softmaxes -> A_eff (fused) ============
__global__ void k34_attn(const float* __restrict__ part, const float* __restrict__ temp,
                         const float* __restrict__ a1, const float* __restrict__ a2,
                         const float* __restrict__ a3, const float* __restrict__ a4,
                         float* __restrict__ Aeff) {
    __shared__ float gbuf[624];
    int bh = blockIdx.x;
    int h = bh & 7;
    int tid = threadIdx.x;
    int lane = tid & 63, wave = tid >> 6;
    int half = lane >> 5, sl = lane & 31;
    for (int tp = wave; tp < 312; tp += 4) {
        int ti = tp * 2 + half;
        float v = part[((size_t)bh * 624 + ti) * 32 + sl];
        v += __shfl_xor(v, 1, 64);
        v += __shfl_xor(v, 2, 64);
        v += __shfl_xor(v, 4, 64);
        v += __shfl_xor(v, 8, 64);
        v += __shfl_xor(v, 16, 64);
        if (sl == 0) gbuf[ti] = v;
    }
    __syncthreads();
    int r = tid;
    if (r >= CDh) return;
    float t = temp[h];
    float aw[4] = {a1[0], a2[0], a3[0], a4[0]};
    const int kks[4] = {12, 16, 18, 19};
    float qn = fmaxf(sqrtf(gbuf[576 + r]), 1e-12f);
    float av[24];
    for (int d = 0; d < 24; d++) {
        float kn = fmaxf(sqrtf(gbuf[600 + d]), 1e-12f);
        av[d] = gbuf[r * 24 + d] / (qn * kn) * t;
    }
    int rank[24];
    float m = -1e30f;
    for (int d = 0; d < 24; d++) {
        int rk = 0;
        for (int e = 0; e < 24; e++)
            rk += (av[e] > av[d]) || (av[e] == av[d] && e < d);
        rank[d] = rk;
        m = fmaxf(m, av[d]);
    }
    float ex[24], outv[24];
    for (int d = 0; d < 24; d++) { ex[d] = expf(av[d] - m); outv[d] = 0.f; }
    for (int i = 0; i < 4; i++) {
        float Z = 0.f;
        for (int d = 0; d < 24; d++) if (rank[d] < kks[i]) Z += ex[d];
        float inv = aw[i] / Z;
        for (int d = 0; d < 24; d++) if (rank[d] < kks[i]) outv[d] += ex[d] * inv;
    }
    for (int d = 0; d < 24; d++) Aeff[(bh * 24 + r) * 24 + d] = outv[d];
}

// ============ K4b: M_b = W_proj @ blockdiag(A_eff) -> bf16 hi/lo ============
__global__ void k4b_mmat(const float* __restrict__ Wp, const float* __restrict__ Aeff,
                         ushort* __restrict__ Mh, ushort* __restrict__ Ml) {
    int b = blockIdx.x;
    int e0 = blockIdx.y * 6144;
    for (int e = e0 + threadIdx.x; e < e0 + 6144; e += 256) {
        int o = e / DIMC, j = e % DIMC;
        int h = j / CDh, d = j % CDh;
        const float* wrow = Wp + o * DIMC + h * CDh;
        const float* acol = Aeff + (size_t)((b * NHEADS + h) * CDh) * CDh + d;
        float s = 0.f;
        for (int c = 0; c < CDh; c++) s = fmaf(wrow[c], acol[c * CDh], s);
        size_t idx = ((size_t)b * DIMC + o) * DIMC + j;
        ushort hb = f2bf(s);
        Mh[idx] = hb;
        Ml[idx] = f2bf(s - bf2f(hb));
    }
}

// ============ K5m fallback: in-place on d_out with LDS convert (R5-proven) ============
__global__ __launch_bounds__(256) void k5m(float* vy,
                                           const ushort* __restrict__ Mh,
                                           const ushort* __restrict__ Ml,
                                           const float* __restrict__ bias) {
    __shared__ float Bs[32 * 132];
    const int z = blockIdx.y;
    float* vb = vy + (size_t)z * DIMC * HWN;
    const ushort* Mhz = Mh + (size_t)z * DIMC * DIMC;
    const ushort* Mlz = Ml + (size_t)z * DIMC * DIMC;
    const int n0 = blockIdx.x * 128;
    const int tid = threadIdx.x;
    const int wid = tid >> 6, lane = tid & 63;
    const int lr = lane & 15, lk = lane >> 4;
    const int mb = wid * 48;
    f32x4 acc[3][8];
#pragma unroll
    for (int i = 0; i < 3; i++)
#pragma unroll
        for (int j = 0; j < 8; j++) acc[i][j] = (f32x4)0.f;

    for (int kc = 0; kc < DIMC; kc += 32) {
        __syncthreads();
#pragma unroll
        for (int it = 0; it < 4; it++) {
            int f4 = tid + it * 256;
            int r = f4 >> 5, c4 = (f4 & 31) * 4;
            *(f32x4*)&Bs[r * 132 + c4] =
                *(const f32x4*)&vb[(size_t)(kc + r) * HWN + n0 + c4];
        }
        __syncthreads();
        short8 bh[8], bl[8];
#pragma unroll
        for (int j = 0; j < 8; j++) {
            int n = j * 16 + lr;
            union { short8 s; uint u[4]; } H, L;
#pragma unroll
            for (int p = 0; p < 4; p++) {
                float v0 = Bs[(lk * 8 + 2 * p) * 132 + n];
                float v1 = Bs[(lk * 8 + 2 * p + 1) * 132 + n];
                ushort h0 = f2bf(v0), h1 = f2bf(v1);
                ushort l0 = f2bf(v0 - bf2f(h0)), l1 = f2bf(v1 - bf2f(h1));
                H.u[p] = (uint)h0 | ((uint)h1 << 16);
                L.u[p] = (uint)l0 | ((uint)l1 << 16);
            }
            bh[j] = H.s; bl[j] = L.s;
        }
#pragma unroll
        for (int i = 0; i < 3; i++) {
            size_t aoff = (size_t)(mb + i * 16 + lr) * DIMC + kc + lk * 8;
            const short8 ah = *(const short8*)&Mhz[aoff];
            const short8 al = *(const short8*)&Mlz[aoff];
#pragma unroll
            for (int j = 0; j < 8; j++) {
                acc[i][j] = __builtin_amdgcn_mfma_f32_16x16x32_bf16(ah, bh[j], acc[i][j], 0, 0, 0);
                acc[i][j] = __builtin_amdgcn_mfma_f32_16x16x32_bf16(ah, bl[j], acc[i][j], 0, 0, 0);
                acc[i][j] = __builtin_amdgcn_mfma_f32_16x16x32_bf16(al, bh[j], acc[i][j], 0, 0, 0);
            }
        }
    }
    __syncthreads();
#pragma unroll
    for (int i = 0; i < 3; i++) {
        int rbase = mb + i * 16 + lk * 4;
#pragma unroll
        for (int r = 0; r < 4; r++) {
            int row = rbase + r;
            float bsv = bias[row];
#pragma unroll
            for (int j = 0; j < 8; j++) {
                vb[(size_t)row * HWN + n0 + j * 16 + lr] = acc[i][j][r] + bsv;
            }
        }
    }
}

extern "C" void kernel_launch(void* const* d_in, const int* in_sizes, int n_in,
                              void* d_out, int out_size, void* d_ws, size_t ws_size,
                              hipStream_t stream) {
    const float* x     = (const float*)d_in[0];
    const float* wqkv  = (const float*)d_in[1];
    const float* bqkv  = (const float*)d_in[2];
    const float* wdw   = (const float*)d_in[3];
    const float* bdw   = (const float*)d_in[4];
    const float* wproj = (const float*)d_in[5];
    const float* bproj = (const float*)d_in[6];
    const float* temp  = (const float*)d_in[7];
    const float* a1    = (const float*)d_in[8];
    const float* a2    = (const float*)d_in[9];
    const float* a3    = (const float*)d_in[10];
    const float* a4    = (const float*)d_in[11];
    float* out = (float*)d_out;

    float* ws = (float*)d_ws;
    const size_t fl_part = (size_t)64 * 624 * 32;
    const size_t fl_A    = (size_t)64 * 576;
    const size_t fl_M    = (size_t)NBATCH * DIMC * DIMC / 2;
    const size_t fl_W    = (size_t)C3 * DIMC / 2;
    const size_t fl_xT1  = (size_t)DIMC * HWN / 2;           // one bf16 buf, one batch
    const size_t fl_qkv1 = (size_t)C3 * HWN;
    const size_t fl_vT1  = (size_t)NBATCH * DIMC * HWN / 2;  // one buf, all batches

    const size_t base_fl = fl_part + fl_A + 2 * fl_M + 2 * fl_W;

    auto needv = [&](int nzz) -> size_t {
        return (base_fl + (size_t)nzz * (2 * fl_xT1 + fl_qkv1) + 2 * fl_vT1) * sizeof(float);
    };
    int vt = 1, nz = 1;
    if (ws_size >= needv(8))      nz = 8;
    else if (ws_size >= needv(4)) nz = 4;
    else if (ws_size >= needv(2)) nz = 2;
    else if (ws_size >= needv(1)) nz = 1;
    else { vt = 0; nz = 1; }

    size_t o = 0;
    float* part = ws + o; o += fl_part;
    float* Aeff = ws + o; o += fl_A;
    ushort* Mh  = (ushort*)(ws + o); o += fl_M;
    ushort* Ml  = (ushort*)(ws + o); o += fl_M;
    ushort* Wh  = (ushort*)(ws + o); o += fl_W;
    ushort* Wl  = (ushort*)(ws + o); o += fl_W;
    ushort* xTh = (ushort*)(ws + o); o += (size_t)nz * fl_xT1;
    ushort* xTl = (ushort*)(ws + o); o += (size_t)nz * fl_xT1;
    float* qkv  = ws + o; o += (size_t)nz * fl_qkv1;
    ushort* vTh = (ushort*)(ws + o); o += vt ? fl_vT1 : 0;
    ushort* vTl = (ushort*)(ws + o);

    const long xT_zs  = (long)DIMC * HWN;   // ushorts per batch
    const long qkv_zs = (long)fl_qkv1;      // floats per batch

    k0_prep<<<(C3 * DIMC + 255) / 256, 256, 0, stream>>>(wqkv, Wh, Wl, C3 * DIMC);

    for (int b0 = 0; b0 < NBATCH; b0 += nz) {
        k0x_tr<<<dim3(256, 3, nz), 256, 0, stream>>>(x, xTh, xTl, xT_zs, b0);
        kg<9><<<dim3(256, 1, nz), 256, 0, stream>>>(xTh, xTl, xT_zs, Wh, Wl, 0L,
                                                    bqkv, qkv, qkv_zs);
        k2_dw<<<dim3(32, 8, nz), 1024, 0, stream>>>(qkv, qkv_zs, wdw, bdw, out,
                                                    vTh, vTl, part, b0, vt);
    }
    k34_attn<<<64, 256, 0, stream>>>(part, temp, a1, a2, a3, a4, Aeff);
    k4b_mmat<<<dim3(8, 6), 256, 0, stream>>>(wproj, Aeff, Mh, Ml);
    if (vt) {
        kg<3><<<dim3(256, 1, 8), 256, 0, stream>>>(vTh, vTl, (long)DIMC * HWN,
                                                   Mh, Ml, (long)DIMC * DIMC,
                                                   bproj, out, (long)DIMC * HWN);
    } else {
        k5m<<<dim3(128, 8), 256, 0, stream>>>(out, Mh, Ml, bproj);
    }
}

// Round 8
// 512.814 us; speedup vs baseline: 1.3740x; 1.1762x over previous
//
#include <hip/hip_runtime.h>
#include <math.h>

#define DIMC 192
#define C3 576
#define NHEADS 8
#define CDh 24
#define HWN 16384
#define WIDTH 128
#define NBATCH 8

typedef __attribute__((ext_vector_type(8))) short short8;
typedef __attribute__((ext_vector_type(4))) float f32x4;

__device__ __forceinline__ ushort f2bf(float f) {
    uint u = __float_as_uint(f);
    u += 0x7fff + ((u >> 16) & 1);
    return (ushort)(u >> 16);
}
__device__ __forceinline__ float bf2f(ushort h) {
    return __uint_as_float(((uint)h) << 16);
}

// ============ K0: split W_qkv -> bf16 hi/lo ============
__global__ void k0_prep(const float* __restrict__ W, ushort* __restrict__ Wh,
                        ushort* __restrict__ Wl, int n) {
    int i = blockIdx.x * 256 + threadIdx.x;
    if (i < n) {
        float w = W[i];
        ushort h = f2bf(w);
        Wh[i] = h;
        Wl[i] = f2bf(w - bf2f(h));
    }
}

// ============ K0x: transpose+split x_b -> xTh/xTl [16384 px][192 ch] bf16 ============
__global__ __launch_bounds__(256) void k0x_tr(const float* __restrict__ x,
                                              ushort* __restrict__ xTh,
                                              ushort* __restrict__ xTl,
                                              long xT_zs, int b0) {
    __shared__ float tile[64 * 65];
    const int z = blockIdx.z;
    const float* xb = x + (size_t)(b0 + z) * DIMC * HWN;
    const int px0 = blockIdx.x * 64, ch0 = blockIdx.y * 64;
    const int tid = threadIdx.x;
#pragma unroll
    for (int it = 0; it < 16; it++) {
        int f = tid + it * 256;
        int row = f >> 6, col = f & 63;
        tile[row * 65 + col] = xb[(size_t)(ch0 + row) * HWN + px0 + col];
    }
    __syncthreads();
    uint* dh = (uint*)(xTh + (size_t)z * xT_zs);
    uint* dl = (uint*)(xTl + (size_t)z * xT_zs);
#pragma unroll
    for (int s = 0; s < 8; s++) {
        int f = tid + s * 256;
        int pxl = f >> 5, uidx = f & 31;
        float v0 = tile[(2 * uidx) * 65 + pxl];
        float v1 = tile[(2 * uidx + 1) * 65 + pxl];
        ushort h0 = f2bf(v0), h1 = f2bf(v1);
        ushort l0 = f2bf(v0 - bf2f(h0)), l1 = f2bf(v1 - bf2f(h1));
        size_t dst = (size_t)(px0 + pxl) * 96 + (ch0 >> 1) + uidx;
        dh[dst] = (uint)h0 | ((uint)h1 << 16);
        dl[dst] = (uint)l0 | ((uint)l1 << 16);
    }
}

// ============ KG<NI>: C = A @ B^T via split-bf16 MFMA, B-tile resident in LDS ============
// grid (256 n-tiles of 64 px, 1, NZ), block 256 (4 waves; wave = NI*16 rows x 64 px).
template <int NI>
__global__ __launch_bounds__(256, (NI == 9) ? 2 : 3) void kg(
    const ushort* __restrict__ Bh, const ushort* __restrict__ Bl, long B_zs,
    const ushort* __restrict__ Ah, const ushort* __restrict__ Al, long A_zs,
    const float* __restrict__ bias, float* __restrict__ out, long out_zs) {
    __shared__ ushort BsH[64 * 200];
    __shared__ ushort BsL[64 * 200];
    const int z = blockIdx.z;
    const int n0 = blockIdx.x * 64;
    const int tid = threadIdx.x;
    const ushort* sh = Bh + (size_t)z * B_zs + (size_t)n0 * DIMC;
    const ushort* sl = Bl + (size_t)z * B_zs + (size_t)n0 * DIMC;
#pragma unroll
    for (int it = 0; it < 6; it++) {
        int f = tid + it * 256;
        int px = f / 24, oct = f - px * 24;
        *(short8*)&BsH[px * 200 + oct * 8] = *(const short8*)&sh[(size_t)px * DIMC + oct * 8];
        *(short8*)&BsL[px * 200 + oct * 8] = *(const short8*)&sl[(size_t)px * DIMC + oct * 8];
    }
    __syncthreads();
    const int wid = tid >> 6, lane = tid & 63;
    const int lr = lane & 15, lk = lane >> 4;
    const int mb = wid * (NI * 16);
    const ushort* Azh = Ah + (size_t)z * A_zs;
    const ushort* Azl = Al + (size_t)z * A_zs;
    float* oz = out + (size_t)z * out_zs;
    f32x4 acc[NI][4];
#pragma unroll
    for (int i = 0; i < NI; i++)
#pragma unroll
        for (int j = 0; j < 4; j++) acc[i][j] = (f32x4)0.f;

    for (int kc6 = 0; kc6 < 6; kc6++) {
        short8 bh[4], bl[4];
#pragma unroll
        for (int j = 0; j < 4; j++) {
            int ad = (j * 16 + lr) * 200 + kc6 * 32 + lk * 8;
            bh[j] = *(const short8*)&BsH[ad];
            bl[j] = *(const short8*)&BsL[ad];
        }
#pragma unroll
        for (int i = 0; i < NI; i++) {
            size_t ao = (size_t)(mb + i * 16 + lr) * DIMC + kc6 * 32 + lk * 8;
            const short8 ah = *(const short8*)&Azh[ao];
            const short8 al = *(const short8*)&Azl[ao];
#pragma unroll
            for (int j = 0; j < 4; j++) {
                acc[i][j] = __builtin_amdgcn_mfma_f32_16x16x32_bf16(ah, bh[j], acc[i][j], 0, 0, 0);
                acc[i][j] = __builtin_amdgcn_mfma_f32_16x16x32_bf16(ah, bl[j], acc[i][j], 0, 0, 0);
                acc[i][j] = __builtin_amdgcn_mfma_f32_16x16x32_bf16(al, bh[j], acc[i][j], 0, 0, 0);
            }
        }
    }
#pragma unroll
    for (int i = 0; i < NI; i++) {
        int rb = mb + i * 16 + lk * 4;
#pragma unroll
        for (int r = 0; r < 4; r++) {
            int row = rb + r;
            float bsv = bias[row];
#pragma unroll
            for (int j = 0; j < 4; j++)
                oz[(size_t)row * HWN + n0 + j * 16 + lr] = acc[i][j][r] + bsv;
        }
    }
}

// ============ KG3F: y = M_b @ v + b_proj, IN-PLACE on d_out; v fp32 staged+split in LDS ============
// grid (256 n-tiles of 64, 8 b), block 256 (4 waves; wave = 48 rows x 64 px).
__global__ __launch_bounds__(256, 3) void kg3f(float* __restrict__ vy,
                                               const ushort* __restrict__ Mh,
                                               const ushort* __restrict__ Ml,
                                               const float* __restrict__ bias) {
    __shared__ ushort BsH[64 * 200];
    __shared__ ushort BsL[64 * 200];
    const int z = blockIdx.y;
    float* vb = vy + (size_t)z * DIMC * HWN;
    const int n0 = blockIdx.x * 64;
    const int tid = threadIdx.x;
    // stage v[all 192 ch][n0..+64) fp32 -> split-bf16 LDS, transposed to [px][ch]
#pragma unroll
    for (int it = 0; it < 12; it++) {
        int idx = tid + it * 256;
        int ch = idx >> 4, q = idx & 15;
        f32x4 v = *(const f32x4*)&vb[(size_t)ch * HWN + n0 + q * 4];
#pragma unroll
        for (int p = 0; p < 4; p++) {
            ushort hb = f2bf(v[p]);
            BsH[(q * 4 + p) * 200 + ch] = hb;
            BsL[(q * 4 + p) * 200 + ch] = f2bf(v[p] - bf2f(hb));
        }
    }
    __syncthreads();
    const int wid = tid >> 6, lane = tid & 63;
    const int lr = lane & 15, lk = lane >> 4;
    const int mb = wid * 48;
    const ushort* Azh = Mh + (size_t)z * DIMC * DIMC;
    const ushort* Azl = Ml + (size_t)z * DIMC * DIMC;
    f32x4 acc[3][4];
#pragma unroll
    for (int i = 0; i < 3; i++)
#pragma unroll
        for (int j = 0; j < 4; j++) acc[i][j] = (f32x4)0.f;

    for (int kc6 = 0; kc6 < 6; kc6++) {
        short8 bh[4], bl[4];
#pragma unroll
        for (int j = 0; j < 4; j++) {
            int ad = (j * 16 + lr) * 200 + kc6 * 32 + lk * 8;
            bh[j] = *(const short8*)&BsH[ad];
            bl[j] = *(const short8*)&BsL[ad];
        }
#pragma unroll
        for (int i = 0; i < 3; i++) {
            size_t ao = (size_t)(mb + i * 16 + lr) * DIMC + kc6 * 32 + lk * 8;
            const short8 ah = *(const short8*)&Azh[ao];
            const short8 al = *(const short8*)&Azl[ao];
#pragma unroll
            for (int j = 0; j < 4; j++) {
                acc[i][j] = __builtin_amdgcn_mfma_f32_16x16x32_bf16(ah, bh[j], acc[i][j], 0, 0, 0);
                acc[i][j] = __builtin_amdgcn_mfma_f32_16x16x32_bf16(ah, bl[j], acc[i][j], 0, 0, 0);
                acc[i][j] = __builtin_amdgcn_mfma_f32_16x16x32_bf16(al, bh[j], acc[i][j], 0, 0, 0);
            }
        }
    }
    // all v reads for this block completed before the barrier -> in-place write safe
#pragma unroll
    for (int i = 0; i < 3; i++) {
        int rb = mb + i * 16 + lk * 4;
#pragma unroll
        for (int r = 0; r < 4; r++) {
            int row = rb + r;
            float bsv = bias[row];
#pragma unroll
            for (int j = 0; j < 4; j++)
                vb[(size_t)row * HWN + n0 + j * 16 + lr] = acc[i][j][r] + bsv;
        }
    }
}

// ============ K2: depthwise 3x3 + Gram/sumsq partials; v -> fp32 d_out ============
// grid (32 stripes of 4 rows, 8 heads, NZ), block 1024 (16 waves).
// Double-buffered stage (1 barrier/chunk); conv neighbors via f32x4 (bank-conflict-free).
__global__ __launch_bounds__(1024, 4) void k2_dw(const float* __restrict__ qkv0, long qkv_zs,
                                                 const float* __restrict__ wdw,
                                                 const float* __restrict__ bdw,
                                                 float* __restrict__ vout,
                                                 float* __restrict__ part, int b0) {
    __shared__ float stage[2 * 6336];   // [2][8][6][132]
    __shared__ float qks[48 * 520];     // [qk ch][512 px + pad], fp32
    const int b = b0 + blockIdx.z;
    const float* qkv = qkv0 + (size_t)blockIdx.z * qkv_zs;
    const int stripe = blockIdx.x, h = blockIdx.y;
    const int tid = threadIdx.x;
    const int r0 = stripe * 4;

    const int col4 = (tid & 31) * 4;
    const int orow = (tid >> 5) & 3;
    const int cc = tid >> 7;  // 0..7

    auto stage_load = [&](int chunk, int buf) {
        const int g = chunk / 3, cb = (chunk % 3) * 8;
        float* sb = stage + buf * 6336;
#pragma unroll
        for (int f = tid; f < 1536; f += 1024) {
            int fc = f / 192, rem = f - fc * 192;
            int rl = rem >> 5, c4 = rem & 31;
            int gr = r0 - 1 + rl;
            int ch = g * DIMC + h * CDh + cb + fc;
            float4 v = make_float4(0.f, 0.f, 0.f, 0.f);
            if (gr >= 0 && gr < 128)
                v = *(const float4*)&qkv[(size_t)ch * HWN + gr * WIDTH + c4 * 4];
            *(float4*)&sb[(fc * 6 + rl) * 132 + c4 * 4] = v;
        }
    };

    stage_load(0, 0);
    __syncthreads();
    for (int chunk = 0; chunk < 9; chunk++) {
        const int buf = chunk & 1;
        if (chunk < 8) stage_load(chunk + 1, buf ^ 1);
        const int g = chunk / 3, cb = (chunk % 3) * 8;
        const float* sb = stage + buf * 6336;
        const int ch = g * DIMC + h * CDh + cb + cc;
        float wr[9];
#pragma unroll
        for (int t = 0; t < 9; t++) wr[t] = wdw[ch * 9 + t];
        float bsv = bdw[ch];
        float a0 = bsv, a1 = bsv, a2 = bsv, a3 = bsv;
#pragma unroll
        for (int dr = 0; dr < 3; dr++) {
            const float* row = &sb[(cc * 6 + orow + dr) * 132];
            f32x4 cen = *(const f32x4*)&row[col4];
            f32x4 lf4 = (col4 > 0) ? *(const f32x4*)&row[col4 - 4] : (f32x4)0.f;
            f32x4 rt4 = (col4 < 124) ? *(const f32x4*)&row[col4 + 4] : (f32x4)0.f;
            float left = lf4[3], right = rt4[0];
            float wA = wr[dr * 3 + 0], wB = wr[dr * 3 + 1], wC = wr[dr * 3 + 2];
            a0 = fmaf(left, wA, fmaf(cen[0], wB, fmaf(cen[1], wC, a0)));
            a1 = fmaf(cen[0], wA, fmaf(cen[1], wB, fmaf(cen[2], wC, a1)));
            a2 = fmaf(cen[1], wA, fmaf(cen[2], wB, fmaf(cen[3], wC, a2)));
            a3 = fmaf(cen[2], wA, fmaf(cen[3], wB, fmaf(right, wC, a3)));
        }
        if (g < 2) {
            float4 o4 = {a0, a1, a2, a3};
            *(float4*)&qks[(g * CDh + cb + cc) * 520 + orow * 128 + col4] = o4;
        } else {
            float4 o4 = {a0, a1, a2, a3};
            *(float4*)&vout[((size_t)b * DIMC + h * CDh + cb + cc) * HWN +
                            (size_t)(r0 + orow) * WIDTH + col4] = o4;
        }
        __syncthreads();
    }

    // Gram: thread = (tc 4, td 4, tp 64 of 8 px); 6x6 register tile
    const int tc = tid & 3, td = (tid >> 2) & 3, tp = tid >> 4;
    float ga[6][6];
#pragma unroll
    for (int i = 0; i < 6; i++)
#pragma unroll
        for (int j = 0; j < 6; j++) ga[i][j] = 0.f;
#pragma unroll
    for (int s = 0; s < 2; s++) {
        int px = tp * 8 + s * 4;
        f32x4 qv[6], kv[6];
#pragma unroll
        for (int i = 0; i < 6; i++) qv[i] = *(const f32x4*)&qks[(tc * 6 + i) * 520 + px];
#pragma unroll
        for (int j = 0; j < 6; j++) kv[j] = *(const f32x4*)&qks[(24 + td * 6 + j) * 520 + px];
#pragma unroll
        for (int i = 0; i < 6; i++)
#pragma unroll
            for (int j = 0; j < 6; j++) {
                ga[i][j] = fmaf(qv[i][0], kv[j][0], ga[i][j]);
                ga[i][j] = fmaf(qv[i][1], kv[j][1], ga[i][j]);
                ga[i][j] = fmaf(qv[i][2], kv[j][2], ga[i][j]);
                ga[i][j] = fmaf(qv[i][3], kv[j][3], ga[i][j]);
            }
    }
#pragma unroll
    for (int i = 0; i < 6; i++)
#pragma unroll
        for (int j = 0; j < 6; j++) {
            float v = ga[i][j];
            v += __shfl_xor(v, 16, 64);
            v += __shfl_xor(v, 32, 64);
            ga[i][j] = v;
        }
    float nv = 0.f;
    int nch = 0, npg = 0;
    if (tid < 768) {
        npg = tid / 48;
        nch = tid - npg * 48;
#pragma unroll
        for (int s = 0; s < 8; s++) {
            f32x4 v = *(const f32x4*)&qks[nch * 520 + npg * 32 + s * 4];
            nv = fmaf(v[0], v[0], nv);
            nv = fmaf(v[1], v[1], nv);
            nv = fmaf(v[2], v[2], nv);
            nv = fmaf(v[3], v[3], nv);
        }
    }
    __syncthreads();
    float* gscr = qks;  // [16][624]
    const int wave = tid >> 6;
    if ((tid & 63) < 16) {
#pragma unroll
        for (int i = 0; i < 6; i++)
#pragma unroll
            for (int j = 0; j < 6; j++)
                gscr[wave * 624 + (tc * 6 + i) * 24 + (td * 6 + j)] = ga[i][j];
    }
    if (tid < 768) gscr[npg * 624 + 576 + nch] = nv;
    __syncthreads();
    if (tid < 624) {
        float s = 0.f;
#pragma unroll
        for (int w2 = 0; w2 < 16; w2++) s += gscr[w2 * 624 + tid];
        part[((size_t)(b * NHEADS + h) * 64 + stripe) * 624 + tid] = s;  // coalesced
    }
}

// ============ K34: reduce partials + attn + 4 top-k softmaxes -> A_eff (fused) ============
// grid 64 (bh), block 256. part layout [bh][64][624].
__global__ void k34_attn(const float* __restrict__ part, const float* __restrict__ temp,
                         const float* __restrict__ a1, const float* __restrict__ a2,
                         const float* __restrict__ a3, const float* __restrict__ a4,
                         float* __restrict__ Aeff) {
    __shared__ float gbuf[624];
    int bh = blockIdx.x;
    int h = bh & 7;
    int tid = threadIdx.x;
    for (int ti = tid; ti < 624; ti += 256) {
        float s = 0.f;
        const float* p = part + (size_t)bh * 64 * 624 + ti;
#pragma unroll 4
        for (int st = 0; st < 64; st++) s += p[st * 624];
        gbuf[ti] = s;
    }
    __syncthreads();
    int r = tid;
    if (r >= CDh) return;
    float t = temp[h];
    float aw[4] = {a1[0], a2[0], a3[0], a4[0]};
    const int kks[4] = {12, 16, 18, 19};
    float qn = fmaxf(sqrtf(gbuf[576 + r]), 1e-12f);
    float av[24];
    for (int d = 0; d < 24; d++) {
        float kn = fmaxf(sqrtf(gbuf[600 + d]), 1e-12f);
        av[d] = gbuf[r * 24 + d] / (qn * kn) * t;
    }
    int rank[24];
    float m = -1e30f;
    for (int d = 0; d < 24; d++) {
        int rk = 0;
        for (int e = 0; e < 24; e++)
            rk += (av[e] > av[d]) || (av[e] == av[d] && e < d);
        rank[d] = rk;
        m = fmaxf(m, av[d]);
    }
    float ex[24], outv[24];
    for (int d = 0; d < 24; d++) { ex[d] = expf(av[d] - m); outv[d] = 0.f; }
    for (int i = 0; i < 4; i++) {
        float Z = 0.f;
        for (int d = 0; d < 24; d++) if (rank[d] < kks[i]) Z += ex[d];
        float inv = aw[i] / Z;
        for (int d = 0; d < 24; d++) if (rank[d] < kks[i]) outv[d] += ex[d] * inv;
    }
    for (int d = 0; d < 24; d++) Aeff[(bh * 24 + r) * 24 + d] = outv[d];
}

// ============ K4b: M_b = W_proj @ blockdiag(A_eff) -> bf16 hi/lo ============
__global__ void k4b_mmat(const float* __restrict__ Wp, const float* __restrict__ Aeff,
                         ushort* __restrict__ Mh, ushort* __restrict__ Ml) {
    int b = blockIdx.x;
    int e0 = blockIdx.y * 6144;
    for (int e = e0 + threadIdx.x; e < e0 + 6144; e += 256) {
        int o = e / DIMC, j = e % DIMC;
        int h = j / CDh, d = j % CDh;
        const float* wrow = Wp + o * DIMC + h * CDh;
        const float* acol = Aeff + (size_t)((b * NHEADS + h) * CDh) * CDh + d;
        float s = 0.f;
        for (int c = 0; c < CDh; c++) s = fmaf(wrow[c], acol[c * CDh], s);
        size_t idx = ((size_t)b * DIMC + o) * DIMC + j;
        ushort hb = f2bf(s);
        Mh[idx] = hb;
        Ml[idx] = f2bf(s - bf2f(hb));
    }
}

extern "C" void kernel_launch(void* const* d_in, const int* in_sizes, int n_in,
                              void* d_out, int out_size, void* d_ws, size_t ws_size,
                              hipStream_t stream) {
    const float* x     = (const float*)d_in[0];
    const float* wqkv  = (const float*)d_in[1];
    const float* bqkv  = (const float*)d_in[2];
    const float* wdw   = (const float*)d_in[3];
    const float* bdw   = (const float*)d_in[4];
    const float* wproj = (const float*)d_in[5];
    const float* bproj = (const float*)d_in[6];
    const float* temp  = (const float*)d_in[7];
    const float* a1    = (const float*)d_in[8];
    const float* a2    = (const float*)d_in[9];
    const float* a3    = (const float*)d_in[10];
    const float* a4    = (const float*)d_in[11];
    float* out = (float*)d_out;

    float* ws = (float*)d_ws;
    const size_t fl_part = (size_t)64 * 64 * 624;            // 2,555,904
    const size_t fl_A    = (size_t)64 * 576;
    const size_t fl_M    = (size_t)NBATCH * DIMC * DIMC / 2;
    const size_t fl_W    = (size_t)C3 * DIMC / 2;
    const size_t fl_xT1  = (size_t)DIMC * HWN / 2;           // one bf16 buf, one batch
    const size_t fl_qkv1 = (size_t)C3 * HWN;
    const size_t base_fl = fl_part + fl_A + 2 * fl_M + 2 * fl_W;

    auto need = [&](int nzz) -> size_t {
        return (base_fl + (size_t)nzz * (2 * fl_xT1 + fl_qkv1)) * sizeof(float);
    };
    int nz = 1;
    if (ws_size >= need(8))      nz = 8;
    else if (ws_size >= need(4)) nz = 4;
    else if (ws_size >= need(2)) nz = 2;

    size_t o = 0;
    float* part = ws + o; o += fl_part;
    float* Aeff = ws + o; o += fl_A;
    ushort* Mh  = (ushort*)(ws + o); o += fl_M;
    ushort* Ml  = (ushort*)(ws + o); o += fl_M;
    ushort* Wh  = (ushort*)(ws + o); o += fl_W;
    ushort* Wl  = (ushort*)(ws + o); o += fl_W;
    ushort* xTh = (ushort*)(ws + o); o += (size_t)nz * fl_xT1;
    ushort* xTl = (ushort*)(ws + o); o += (size_t)nz * fl_xT1;
    float* qkv  = ws + o;

    const long xT_zs  = (long)DIMC * HWN;   // ushorts per batch
    const long qkv_zs = (long)fl_qkv1;      // floats per batch

    k0_prep<<<(C3 * DIMC + 255) / 256, 256, 0, stream>>>(wqkv, Wh, Wl, C3 * DIMC);

    for (int b0 = 0; b0 < NBATCH; b0 += nz) {
        k0x_tr<<<dim3(256, 3, nz), 256, 0, stream>>>(x, xTh, xTl, xT_zs, b0);
        kg<9><<<dim3(256, 1, nz), 256, 0, stream>>>(xTh, xTl, xT_zs, Wh, Wl, 0L,
                                                    bqkv, qkv, qkv_zs);
        k2_dw<<<dim3(32, 8, nz), 1024, 0, stream>>>(qkv, qkv_zs, wdw, bdw, out, part, b0);
    }
    k34_attn<<<64, 256, 0, stream>>>(part, temp, a1, a2, a3, a4, Aeff);
    k4b_mmat<<<dim3(8, 6), 256, 0, stream>>>(wproj, Aeff, Mh, Ml);
    kg3f<<<dim3(256, 8), 256, 0, stream>>>(out, Mh, Ml, bproj);
}